// Round 10
// baseline (258.536 us; speedup 1.0000x reference)
//
#include <hip/hip_runtime.h>
#include <stdint.h>

namespace {

typedef _Float16 f16x8 __attribute__((ext_vector_type(8)));
typedef float f32x16 __attribute__((ext_vector_type(16)));

__device__ __forceinline__ uint32_t pkrtz(float a, float b) {
  return __builtin_bit_cast(uint32_t, __builtin_amdgcn_cvt_pkrtz(a, b));
}

constexpr int IMG = 512, K = 51;
constexpr int NT = 512;     // 8 waves: (group g) x (row parity) x (i-half)
constexpr int XB = 64;      // pixels per block
constexpr int YB = 8;       // output rows per block
constexpr int NSS = YB / 2; // 4 supersteps
constexpr int FSLOTS = 52;  // frame row ring
constexpr int FG = 15;      // 16B granules per channel-row = 120 f16 cols
constexpr int HP = 26;      // u32 pitch of H pair-table per x
constexpr int NQ = 6;       // K=16 chunks

// frame tile: [ch 3][granule 15][slot 52][8 f16] = 37440 B
// H table   : [par 2][x 64][26 u32]              = 13312 B
// exchange  : [2][2][3][32] f32                  =  1536 B   (total 52288 B)
constexpr int FR_U16 = 3 * FG * FSLOTS * 8;
constexpr int H_U32  = 2 * 64 * HP;
constexpr int EX_F32 = 2 * 2 * 3 * 32;
constexpr int CH_B   = FG * FSLOTS * 16;   // 12480 B per channel
constexpr int GR_B   = FSLOTS * 16;        // 832 B per granule

__global__ __launch_bounds__(NT, 4)   // 4 waves/EU min -> 128-reg budget, 2 blk/CU
void sepconv(const float* __restrict__ fr0, const float* __restrict__ fr2,
             const float* __restrict__ V1, const float* __restrict__ H1,
             const float* __restrict__ V2, const float* __restrict__ H2,
             float* __restrict__ out)
{
  __shared__ __align__(16) uint16_t frL[FR_U16];
  __shared__ uint32_t hL[H_U32];
  __shared__ float exL[EX_F32];
  uint32_t* fr32 = (uint32_t*)frL;

  const int tid = threadIdx.x;
  const int l    = tid & 63;
  const int w    = tid >> 6;
  const int g    = w & 1;          // 32-px group
  const int ypar = (w >> 1) & 1;   // row parity
  const int ih   = w >> 2;         // i-half: 0 -> taps 0..18, 1 -> taps 19..50
  const int n    = l & 31;         // pixel in group
  const int kb   = l >> 5;         // k-half
  const int x0   = blockIdx.x * XB;
  const int y0   = blockIdx.y * YB;
  const int b    = blockIdx.z;
  const size_t plane = (size_t)IMG * IMG;
  const int xloc = 32 * g + n;

  // H staging role: 2 rows x 4 segments x 64 px = 512 threads exactly
  const int hx = tid & 63, hseg = (tid >> 6) & 3, hyy = tid >> 8;
  const int segp0 = (hseg == 0) ? 0 : (hseg == 1) ? 7 : (hseg == 2) ? 13 : 20;
  const int segn  = (hseg & 1) ? 6 : 7;
  // frame-carry role: 2 rows x 3 ch x 60 pairs = 360 tasks
  const bool hasfc = tid < 360;
  const int rr0 = tid / 180, c0 = (tid % 180) / 60, pc0 = tid % 60;
  const int sca0 = min(max(x0 - 25 + 2 * pc0, 0), IMG - 1);
  const int scb0 = min(max(x0 - 25 + 2 * pc0 + 1, 0), IMG - 1);

  #pragma unroll 1
  for (int f = 0; f < 2; ++f) {
    const float* __restrict__ Vf = (f ? V2 : V1) + (size_t)b * K * plane;
    const float* __restrict__ Hf = (f ? H2 : H1) + (size_t)b * K * plane;
    const float* __restrict__ frb =
        (f ? fr2 : fr0) + (size_t)b * 3 * plane;

    float ha[7], hb[7], fc0 = 0.f, fc1 = 0.f;   // distance-1 carries

    __syncthreads();   // previous pass's LDS reads complete

    // ---- prologue: H rows y0,y0+1 (loads issued first) ----
    float pha[7], phb[7];
    {
      const int yH = y0 + hyy;
      #pragma unroll
      for (int m = 0; m < 7; ++m)
        if (m < segn) {
          int p = segp0 + m, j0 = 2 * p;
          pha[m] = Hf[(size_t)j0 * plane + (size_t)yH * IMG + x0 + hx];
          phb[m] = (j0 + 1 <= 50)
                 ? Hf[(size_t)(j0 + 1) * plane + (size_t)yH * IMG + x0 + hx]
                 : 0.f;
        }
    }
    // ---- prologue: frame rows y0-25..y0+26 (9360 pair-tasks, 2 passes) ----
    #pragma unroll 1
    for (int pass = 0; pass < 2; ++pass) {
      float ta[10], tb[10];
      #pragma unroll
      for (int k2 = 0; k2 < 10; ++k2) {
        int task = tid + NT * (pass * 10 + k2);
        if (task < 9360) {
          int rr = task / 180; int rem = task - rr * 180;
          int c = rem / 60, pc = rem - c * 60;
          int row = min(max(y0 - 25 + rr, 0), IMG - 1);
          int ca = min(max(x0 - 25 + 2 * pc, 0), IMG - 1);
          int cb = min(max(x0 - 25 + 2 * pc + 1, 0), IMG - 1);
          const float* rp = frb + (size_t)c * plane + (size_t)row * IMG;
          ta[k2] = rp[ca]; tb[k2] = rp[cb];
        }
      }
      if (pass == 0) {   // H-table writes overlapped under pass-0 loads
        #pragma unroll
        for (int m = 0; m < 7; ++m)
          if (m < segn)
            hL[(hyy * 64 + hx) * HP + segp0 + m] = pkrtz(pha[m], phb[m]);
      }
      #pragma unroll
      for (int k2 = 0; k2 < 10; ++k2) {
        int task = tid + NT * (pass * 10 + k2);
        if (task < 9360) {
          int rr = task / 180; int rem = task - rr * 180;
          int c = rem / 60, pc = rem - c * 60;
          int slot = (y0 - 25 + rr + 520) % 52;
          fr32[((c * FG + (pc >> 2)) * FSLOTS + slot) * 4 + (pc & 3)] =
              pkrtz(ta[k2], tb[k2]);
        }
      }
    }
    __syncthreads();

    #pragma unroll 1
    for (int s = 0; s < NSS; ++s) {
      const int y = y0 + 2 * s;
      if (s > 0) {
        __syncthreads();
        // write carries loaded at superstep s-1 (latency fully covered)
        if (hasfc) {
          int slot0 = (y + 25 + rr0 + 520) % 52;
          fr32[((c0 * FG + (pc0 >> 2)) * FSLOTS + slot0) * 4 + (pc0 & 3)] =
              pkrtz(fc0, fc1);
        }
        #pragma unroll
        for (int m = 0; m < 7; ++m)
          if (m < segn)
            hL[(hyy * 64 + hx) * HP + segp0 + m] = pkrtz(ha[m], hb[m]);
        __syncthreads();
      }
      const int yw = y + ypar;

      // ---- V loads (i-range split across ih: no duplicated traffic) ----
      float v[16], vx[3] = {0.f, 0.f, 0.f};
      {
        const float* vb = Vf + (size_t)yw * IMG + x0 + xloc
                          + (size_t)kb * 4 * plane;
        if (ih) {
          const float* vb1 = vb + (size_t)19 * plane;
          #pragma unroll
          for (int r = 0; r < 16; ++r)
            v[r] = vb1[(size_t)((r & 3) + 8 * (r >> 2)) * plane];
        } else {
          #pragma unroll
          for (int r = 0; r < 8; ++r)
            v[r] = vb[(size_t)((r & 3) + 8 * (r >> 2)) * plane];
          if (kb == 0) {
            vx[0] = vb[(size_t)16 * plane];
            vx[1] = vb[(size_t)17 * plane];
            vx[2] = vb[(size_t)18 * plane];
          }
        }
      }
      float op[3] = {0.f, 0.f, 0.f};
      if (f == 1 && ih == 0 && l < 32) {
        #pragma unroll
        for (int c = 0; c < 3; ++c)
          op[c] = out[((size_t)(b * 3 + c) * IMG + yw) * IMG + x0 + xloc];
      }
      // ---- carry loads for superstep s+1 ----
      if (s + 1 < NSS) {
        const int yH = y + 2 + hyy;
        #pragma unroll
        for (int m = 0; m < 7; ++m)
          if (m < segn) {
            int p = segp0 + m, j0 = 2 * p;
            ha[m] = Hf[(size_t)j0 * plane + (size_t)yH * IMG + x0 + hx];
            hb[m] = (j0 + 1 <= 50)
                  ? Hf[(size_t)(j0 + 1) * plane + (size_t)yH * IMG + x0 + hx]
                  : 0.f;
          }
        if (hasfc) {
          int row0 = min(y + 27 + rr0, IMG - 1);
          const float* rp = frb + (size_t)c0 * plane + (size_t)row0 * IMG;
          fc0 = rp[sca0]; fc1 = rp[scb0];
        }
      }

      // ---- B fragments: banded per-pixel H (6 chunks of K=16) ----
      uint4 Bq[NQ];
      {
        const uint32_t* hrow = hL + (ypar * 64 + xloc) * HP;
        #pragma unroll
        for (int q = 0; q < NQ; ++q) {
          int j0 = 16 * q + 8 * kb - n;
          int pb = j0 >> 1;
          uint32_t rd[5];
          #pragma unroll
          for (int ww = 0; ww < 5; ++ww) {
            int pw = pb + ww;
            bool ok = (unsigned)pw <= 25u;
            uint32_t vr = hrow[ok ? pw : 0];
            rd[ww] = ok ? vr : 0u;
          }
          uint32_t fv[4];
          #pragma unroll
          for (int v2 = 0; v2 < 4; ++v2) {
            uint32_t al =
                (uint32_t)((((uint64_t)rd[v2 + 1] << 32) | rd[v2]) >> 16);
            fv[v2] = (n & 1) ? al : rd[v2];
          }
          Bq[q] = make_uint4(fv[0], fv[1], fv[2], fv[3]);
        }
      }

      // ---- A ring base for this wave's tile ----
      int sbase = (ih ? (yw - 6) : (yw - 25)) + 520;
      int slot = sbase % 52 + n; if (slot >= 52) slot -= 52;
      const char* pA = (const char*)frL + (4 * g + kb) * GR_B + slot * 16;
      // g=1,kb=1,q=5 would read granule 15 (not staged); its B is all-zero
      // (taps j>=57), so redirect to a staged granule: finite * 0 = 0.
      const int q5adj = (g & kb) ? -(2 * GR_B) : 0;

      float pa[3];
      #pragma unroll
      for (int c = 0; c < 3; ++c) {
        f32x16 D;
        #pragma unroll
        for (int e = 0; e < 16; ++e) D[e] = 0.f;
        #pragma unroll
        for (int q = 0; q < NQ; ++q) {
          const f16x8 A = *(const f16x8*)(pA + c * CH_B + q * (2 * GR_B)
                                          + (q == 5 ? q5adj : 0));
          D = __builtin_amdgcn_mfma_f32_32x32x16_f16(
                  A, __builtin_bit_cast(f16x8, Bq[q]), D, 0, 0, 0);
        }
        float a = 0.f;
        if (ih) {
          #pragma unroll
          for (int r = 0; r < 16; ++r) a += v[r] * D[r];
        } else {
          #pragma unroll
          for (int r = 0; r < 8; ++r) a += v[r] * D[r];
          a += vx[0] * D[8] + vx[1] * D[9] + vx[2] * D[10];
        }
        a += __shfl_xor(a, 32, 64);
        pa[c] = a;
      }

      // ---- cross-ih reduce via LDS exchange + store (RMW on frame 1) ----
      if (ih == 1 && l < 32) {
        #pragma unroll
        for (int c = 0; c < 3; ++c)
          exL[((g * 2 + ypar) * 3 + c) * 32 + l] = pa[c];
      }
      __syncthreads();
      if (ih == 0 && l < 32) {
        #pragma unroll
        for (int c = 0; c < 3; ++c) {
          float t = pa[c] + exL[((g * 2 + ypar) * 3 + c) * 32 + l];
          size_t oidx = ((size_t)(b * 3 + c) * IMG + yw) * IMG + x0 + xloc;
          out[oidx] = (f == 0) ? t : (op[c] + t);
        }
      }
    }
  }
}

} // namespace

extern "C" void kernel_launch(void* const* d_in, const int* in_sizes, int n_in,
                              void* d_out, int out_size, void* d_ws, size_t ws_size,
                              hipStream_t stream)
{
  const float* frame0 = (const float*)d_in[0];
  const float* frame2 = (const float*)d_in[1];
  const float* V1 = (const float*)d_in[2];
  const float* H1 = (const float*)d_in[3];
  const float* V2 = (const float*)d_in[4];
  const float* H2 = (const float*)d_in[5];
  float* o = (float*)d_out;

  dim3 grid(IMG / XB, IMG / YB, 2);
  dim3 block(NT);
  hipLaunchKernelGGL(sepconv, grid, block, 0, stream,
                     frame0, frame2, V1, H1, V2, H2, o);
}

// Round 11
// 179.682 us; speedup vs baseline: 1.4389x; 1.4389x over previous
//
#include <hip/hip_runtime.h>
#include <stdint.h>

namespace {

typedef _Float16 f16x8 __attribute__((ext_vector_type(8)));
typedef float f32x16 __attribute__((ext_vector_type(16)));

__device__ __forceinline__ uint32_t pkrtz(float a, float b) {
  return __builtin_bit_cast(uint32_t, __builtin_amdgcn_cvt_pkrtz(a, b));
}

constexpr int IMG = 512, K = 51;
constexpr int NT = 512;     // 8 waves: (group g) x (row parity) x (i-half)
constexpr int XB = 64;      // pixels per block
constexpr int YB = 8;       // output rows per block
constexpr int NSS = YB / 2; // 4 supersteps
constexpr int FROWS = 59;   // static rows y0-25 .. y0+33 (no ring)
constexpr int FG = 15;      // 16B granules per channel-row = 120 f16 cols
constexpr int HP = 26;      // u32 pitch of H pair-table per x
constexpr int NQ = 6;       // K=16 chunks

constexpr int GR_B  = FROWS * 16;        // 944 B per granule
constexpr int CH_B  = FG * GR_B;         // 14160 B per channel
constexpr int FR_U32 = 3 * FG * FROWS;   // frame tile u32 granule-quads *4
constexpr int H_U32  = 2 * 64 * HP;      // 13312 B
constexpr int EX_F32 = 4 * 2 * 2 * 2 * 3 * 32;  // 12288 B
// LDS total: 42480 + 13312 + 12288 = 68080 B -> 2 blocks/CU, 16 waves/CU

__device__ __forceinline__ int exidx(int s, int ih, int g, int yp, int c, int n) {
  return ((((s * 2 + ih) * 2 + g) * 2 + yp) * 3 + c) * 32 + n;
}

__global__ __launch_bounds__(NT, 4)
void sepconv(const float* __restrict__ fr0, const float* __restrict__ fr2,
             const float* __restrict__ V1, const float* __restrict__ H1,
             const float* __restrict__ V2, const float* __restrict__ H2,
             float* __restrict__ out)
{
  __shared__ __align__(16) uint32_t fr32[FR_U32 * 4];
  __shared__ uint32_t hL[H_U32];
  __shared__ float exL[EX_F32];

  const int tid = threadIdx.x;
  const int l    = tid & 63;
  const int w    = tid >> 6;
  const int g    = w & 1;          // 32-px group
  const int ypar = (w >> 1) & 1;   // row parity
  const int ih   = w >> 2;         // i-half: 0 -> taps 0..18, 1 -> taps 19..50
  const int n    = l & 31;         // pixel in group
  const int kb   = l >> 5;         // k-half
  const int x0   = blockIdx.x * XB;
  const int y0   = blockIdx.y * YB;
  const int b    = blockIdx.z;
  const size_t plane = (size_t)IMG * IMG;
  const int xloc = 32 * g + n;

  // H staging role: 2 rows x 4 segments x 64 px = 512 threads exactly
  const int hx = tid & 63, hseg = (tid >> 6) & 3, hyy = tid >> 8;
  const int segp0 = (hseg == 0) ? 0 : (hseg == 1) ? 7 : (hseg == 2) ? 13 : 20;
  const int segn  = (hseg & 1) ? 6 : 7;

  #pragma unroll 1
  for (int f = 0; f < 2; ++f) {
    const float* __restrict__ Vf = (f ? V2 : V1) + (size_t)b * K * plane;
    const float* __restrict__ Hf = (f ? H2 : H1) + (size_t)b * K * plane;
    const float* __restrict__ frb = (f ? fr2 : fr0) + (size_t)b * 3 * plane;

    float ha[7], hb[7];     // distance-1 H carries

    __syncthreads();   // previous pass's LDS reads (incl. final phase) done

    // ---- prologue: H rows y0,y0+1 (loads issued first) ----
    float pha[7], phb[7];
    {
      const int yH = y0 + hyy;
      #pragma unroll
      for (int m = 0; m < 7; ++m)
        if (m < segn) {
          int p = segp0 + m, j0 = 2 * p;
          pha[m] = Hf[(size_t)j0 * plane + (size_t)yH * IMG + x0 + hx];
          phb[m] = (j0 + 1 <= 50)
                 ? Hf[(size_t)(j0 + 1) * plane + (size_t)yH * IMG + x0 + hx]
                 : 0.f;
        }
    }
    // ---- prologue: frame rows y0-25..y0+33 (10620 pair-tasks, 3 passes) ----
    #pragma unroll 1
    for (int pass = 0; pass < 3; ++pass) {
      float ta[7], tb[7];
      #pragma unroll
      for (int k2 = 0; k2 < 7; ++k2) {
        int task = tid + NT * (pass * 7 + k2);
        if (task < 10620) {
          int rr = task / 180; int rem = task - rr * 180;
          int c = rem / 60, pc = rem - c * 60;
          int row = min(max(y0 - 25 + rr, 0), IMG - 1);
          int ca = min(max(x0 - 25 + 2 * pc, 0), IMG - 1);
          int cb = min(max(x0 - 25 + 2 * pc + 1, 0), IMG - 1);
          const float* rp = frb + (size_t)c * plane + (size_t)row * IMG;
          ta[k2] = rp[ca]; tb[k2] = rp[cb];
        }
      }
      if (pass == 0) {   // H-table writes overlapped under pass-0 loads
        #pragma unroll
        for (int m = 0; m < 7; ++m)
          if (m < segn)
            hL[(hyy * 64 + hx) * HP + segp0 + m] = pkrtz(pha[m], phb[m]);
      }
      #pragma unroll
      for (int k2 = 0; k2 < 7; ++k2) {
        int task = tid + NT * (pass * 7 + k2);
        if (task < 10620) {
          int rr = task / 180; int rem = task - rr * 180;
          int c = rem / 60, pc = rem - c * 60;
          fr32[((c * FG + (pc >> 2)) * FROWS + rr) * 4 + (pc & 3)] =
              pkrtz(ta[k2], tb[k2]);
        }
      }
    }
    __syncthreads();

    #pragma unroll 1
    for (int s = 0; s < NSS; ++s) {
      const int y = y0 + 2 * s;
      if (s > 0) {
        __syncthreads();   // previous superstep's hL reads complete
        #pragma unroll
        for (int m = 0; m < 7; ++m)
          if (m < segn)
            hL[(hyy * 64 + hx) * HP + segp0 + m] = pkrtz(ha[m], hb[m]);
        __syncthreads();   // H table visible
      }
      const int yw = y + ypar;

      // ---- V loads issued at superstep top (consumed in epilogue) ----
      float v[16], vx[3] = {0.f, 0.f, 0.f};
      {
        const float* vb = Vf + (size_t)yw * IMG + x0 + xloc
                          + (size_t)kb * 4 * plane;
        if (ih) {
          const float* vb1 = vb + (size_t)19 * plane;
          #pragma unroll
          for (int r = 0; r < 16; ++r)
            v[r] = vb1[(size_t)((r & 3) + 8 * (r >> 2)) * plane];
        } else {
          #pragma unroll
          for (int r = 0; r < 8; ++r)
            v[r] = vb[(size_t)((r & 3) + 8 * (r >> 2)) * plane];
          if (kb == 0) {
            vx[0] = vb[(size_t)16 * plane];
            vx[1] = vb[(size_t)17 * plane];
            vx[2] = vb[(size_t)18 * plane];
          }
          #pragma unroll
          for (int r = 8; r < 16; ++r) v[r] = 0.f;
        }
      }

      // ---- B fragments: banded per-pixel H (6 chunks of K=16) ----
      uint4 Bq[NQ];
      {
        const uint32_t* hrow = hL + (ypar * 64 + xloc) * HP;
        #pragma unroll
        for (int q = 0; q < NQ; ++q) {
          int j0 = 16 * q + 8 * kb - n;
          int pb = j0 >> 1;
          uint32_t rd[5];
          #pragma unroll
          for (int ww = 0; ww < 5; ++ww) {
            int pw = pb + ww;
            bool ok = (unsigned)pw <= 25u;
            uint32_t vr = hrow[ok ? pw : 0];
            rd[ww] = ok ? vr : 0u;
          }
          uint32_t fv[4];
          #pragma unroll
          for (int v2 = 0; v2 < 4; ++v2) {
            uint32_t al =
                (uint32_t)((((uint64_t)rd[v2 + 1] << 32) | rd[v2]) >> 16);
            fv[v2] = (n & 1) ? al : rd[v2];
          }
          Bq[q] = make_uint4(fv[0], fv[1], fv[2], fv[3]);
        }
      }

      // ---- H-carry loads for s+1 (hidden under MFMA cluster) ----
      if (s + 1 < NSS) {
        const int yH = y + 2 + hyy;
        #pragma unroll
        for (int m = 0; m < 7; ++m)
          if (m < segn) {
            int p = segp0 + m, j0 = 2 * p;
            ha[m] = Hf[(size_t)j0 * plane + (size_t)yH * IMG + x0 + hx];
            hb[m] = (j0 + 1 <= 50)
                  ? Hf[(size_t)(j0 + 1) * plane + (size_t)yH * IMG + x0 + hx]
                  : 0.f;
          }
      }

      // ---- A base (static slot, no ring) ----
      const int lr = (ih ? 19 : 0) + 2 * s + ypar + n;   // local row
      const char* pA = (const char*)fr32 + (4 * g + kb) * GR_B + lr * 16;
      // g=1,kb=1,q=5 would read granule 15 (not staged); B there is all-zero
      // (taps j>=57), so redirect to a staged granule: finite * 0 = 0.
      const int q5adj = (g & kb) ? -(2 * GR_B) : 0;

      __builtin_amdgcn_s_setprio(1);
      float pa[3];
      #pragma unroll
      for (int c = 0; c < 3; ++c) {
        f32x16 D;
        #pragma unroll
        for (int e = 0; e < 16; ++e) D[e] = 0.f;
        #pragma unroll
        for (int q = 0; q < NQ; ++q) {
          const f16x8 A = *(const f16x8*)(pA + c * CH_B + q * (2 * GR_B)
                                          + (q == 5 ? q5adj : 0));
          D = __builtin_amdgcn_mfma_f32_32x32x16_f16(
                  A, __builtin_bit_cast(f16x8, Bq[q]), D, 0, 0, 0);
        }
        float a = 0.f;
        if (ih) {
          #pragma unroll
          for (int r = 0; r < 16; ++r) a += v[r] * D[r];
        } else {
          #pragma unroll
          for (int r = 0; r < 8; ++r) a += v[r] * D[r];
          a += vx[0] * D[8] + vx[1] * D[9] + vx[2] * D[10];
        }
        a += __shfl_xor(a, 32, 64);
        pa[c] = a;
      }
      __builtin_amdgcn_s_setprio(0);

      // ---- dump partials (reduced in final phase) ----
      if (l < 32) {
        #pragma unroll
        for (int c = 0; c < 3; ++c)
          exL[exidx(s, ih, g, ypar, c, l)] = pa[c];
      }
    }

    // ---- final phase: reduce ih-halves, coalesced (RMW) store ----
    __syncthreads();
    #pragma unroll
    for (int t = 0; t < 3; ++t) {
      int oi = tid + NT * t;          // 1536 outputs
      int px = oi & 63, rem = oi >> 6;
      int c = rem % 3, r = rem / 3;
      int ss = r >> 1, yp = r & 1, gg = px >> 5, nn = px & 31;
      float val = exL[exidx(ss, 0, gg, yp, c, nn)]
                + exL[exidx(ss, 1, gg, yp, c, nn)];
      size_t oidx = ((size_t)(b * 3 + c) * IMG + y0 + r) * IMG + x0 + px;
      out[oidx] = (f == 0) ? val : (out[oidx] + val);
    }
  }
}

} // namespace

extern "C" void kernel_launch(void* const* d_in, const int* in_sizes, int n_in,
                              void* d_out, int out_size, void* d_ws, size_t ws_size,
                              hipStream_t stream)
{
  const float* frame0 = (const float*)d_in[0];
  const float* frame2 = (const float*)d_in[1];
  const float* V1 = (const float*)d_in[2];
  const float* H1 = (const float*)d_in[3];
  const float* V2 = (const float*)d_in[4];
  const float* H2 = (const float*)d_in[5];
  float* o = (float*)d_out;

  dim3 grid(IMG / XB, IMG / YB, 2);
  dim3 block(NT);
  hipLaunchKernelGGL(sepconv, grid, block, 0, stream,
                     frame0, frame2, V1, H1, V2, H2, o);
}

// Round 12
// 161.184 us; speedup vs baseline: 1.6040x; 1.1148x over previous
//
#include <hip/hip_runtime.h>
#include <stdint.h>

namespace {

typedef _Float16 f16x8 __attribute__((ext_vector_type(8)));
typedef float f32x16 __attribute__((ext_vector_type(16)));

__device__ __forceinline__ uint32_t pkrtz(float a, float b) {
  return __builtin_bit_cast(uint32_t, __builtin_amdgcn_cvt_pkrtz(a, b));
}

constexpr int IMG = 512, K = 51;
constexpr int NT = 512;     // 8 waves: (group g) x (row parity) x (i-half)
constexpr int XB = 64;      // pixels per block
constexpr int YB = 8;       // output rows per block
constexpr int NSS = YB / 2; // 4 supersteps
constexpr int FROWS = 59;   // static rows y0-25 .. y0+33 (no ring)
constexpr int FG = 15;      // 16B granules per channel-row = 120 f16 cols
constexpr int HP = 26;      // u32 pitch of H pair-table per x
constexpr int NQ = 6;       // K=16 chunks

constexpr int GR_B  = FROWS * 16;        // 944 B per granule
constexpr int CH_B  = FG * GR_B;         // 14160 B per channel
constexpr int FR_U32 = 3 * FG * FROWS;   // frame tile granule-quads (*4 u32)
constexpr int H_U32  = 2 * 64 * HP;      // 13312 B
constexpr int EX_F32 = 4 * 2 * 2 * 2 * 3 * 32;  // 12288 B
// LDS total: 42480 + 13312 + 12288 = 68080 B -> 2 blocks/CU, 16 waves/CU

__device__ __forceinline__ int exidx(int s, int ih, int g, int yp, int c, int n) {
  return ((((s * 2 + ih) * 2 + g) * 2 + yp) * 3 + c) * 32 + n;
}

__global__ __launch_bounds__(NT, 4)
void sepconv(const float* __restrict__ fr0, const float* __restrict__ fr2,
             const float* __restrict__ V1, const float* __restrict__ H1,
             const float* __restrict__ V2, const float* __restrict__ H2,
             float* __restrict__ out)
{
  __shared__ __align__(16) uint32_t fr32[FR_U32 * 4];
  __shared__ uint32_t hL[H_U32];
  __shared__ float exL[EX_F32];

  const int tid = threadIdx.x;
  const int l    = tid & 63;
  const int w    = tid >> 6;
  const int g    = w & 1;          // 32-px group
  const int ypar = (w >> 1) & 1;   // row parity
  const int ih   = w >> 2;         // i-half: 0 -> taps 0..18, 1 -> taps 19..50
  const int n    = l & 31;         // pixel in group
  const int kb   = l >> 5;         // k-half
  const int x0   = blockIdx.x * XB;
  const int y0   = blockIdx.y * YB;
  const int b    = blockIdx.z;
  const size_t plane = (size_t)IMG * IMG;
  const int xloc = 32 * g + n;

  // H staging role: 2 rows x 4 segments x 64 px = 512 threads exactly
  const int hx = tid & 63, hseg = (tid >> 6) & 3, hyy = tid >> 8;
  const int segp0 = (hseg == 0) ? 0 : (hseg == 1) ? 7 : (hseg == 2) ? 13 : 20;
  const int segn  = (hseg & 1) ? 6 : 7;

  #pragma unroll 1
  for (int f = 0; f < 2; ++f) {
    const float* __restrict__ Vf = (f ? V2 : V1) + (size_t)b * K * plane;
    const float* __restrict__ Hf = (f ? H2 : H1) + (size_t)b * K * plane;
    const float* __restrict__ frb = (f ? fr2 : fr0) + (size_t)b * 3 * plane;

    float ha[7], hb[7];     // distance-1 H carries

    __syncthreads();   // previous pass's LDS reads (incl. final phase) done

    // ---- prologue: H rows y0,y0+1 (loads issued first) ----
    float pha[7], phb[7];
    {
      const int yH = y0 + hyy;
      #pragma unroll
      for (int m = 0; m < 7; ++m)
        if (m < segn) {
          int p = segp0 + m, j0 = 2 * p;
          pha[m] = Hf[(size_t)j0 * plane + (size_t)yH * IMG + x0 + hx];
          phb[m] = (j0 + 1 <= 50)
                 ? Hf[(size_t)(j0 + 1) * plane + (size_t)yH * IMG + x0 + hx]
                 : 0.f;
        }
    }
    // ---- prologue: frame rows y0-25..y0+33 (10620 pair-tasks, 3 passes) ----
    #pragma unroll 1
    for (int pass = 0; pass < 3; ++pass) {
      float ta[7], tb[7];
      #pragma unroll
      for (int k2 = 0; k2 < 7; ++k2) {
        int task = tid + NT * (pass * 7 + k2);
        if (task < 10620) {
          int rr = task / 180; int rem = task - rr * 180;
          int c = rem / 60, pc = rem - c * 60;
          int row = min(max(y0 - 25 + rr, 0), IMG - 1);
          int ca = min(max(x0 - 25 + 2 * pc, 0), IMG - 1);
          int cb = min(max(x0 - 25 + 2 * pc + 1, 0), IMG - 1);
          const float* rp = frb + (size_t)c * plane + (size_t)row * IMG;
          ta[k2] = rp[ca]; tb[k2] = rp[cb];
        }
      }
      if (pass == 0) {   // H-table writes overlapped under pass-0 loads
        #pragma unroll
        for (int m = 0; m < 7; ++m)
          if (m < segn)
            hL[(hyy * 64 + hx) * HP + segp0 + m] = pkrtz(pha[m], phb[m]);
      }
      #pragma unroll
      for (int k2 = 0; k2 < 7; ++k2) {
        int task = tid + NT * (pass * 7 + k2);
        if (task < 10620) {
          int rr = task / 180; int rem = task - rr * 180;
          int c = rem / 60, pc = rem - c * 60;
          fr32[((c * FG + (pc >> 2)) * FROWS + rr) * 4 + (pc & 3)] =
              pkrtz(ta[k2], tb[k2]);
        }
      }
    }
    __syncthreads();

    #pragma unroll 1
    for (int s = 0; s < NSS; ++s) {
      const int y = y0 + 2 * s;
      if (s > 0) {
        __syncthreads();   // previous superstep's hL reads complete
        #pragma unroll
        for (int m = 0; m < 7; ++m)
          if (m < segn)
            hL[(hyy * 64 + hx) * HP + segp0 + m] = pkrtz(ha[m], hb[m]);
        __syncthreads();   // H table visible
      }
      const int yw = y + ypar;

      // ---- H-carry loads for s+1: issued first (consumed next superstep) --
      if (s + 1 < NSS) {
        const int yH = y + 2 + hyy;
        #pragma unroll
        for (int m = 0; m < 7; ++m)
          if (m < segn) {
            int p = segp0 + m, j0 = 2 * p;
            ha[m] = Hf[(size_t)j0 * plane + (size_t)yH * IMG + x0 + hx];
            hb[m] = (j0 + 1 <= 50)
                  ? Hf[(size_t)(j0 + 1) * plane + (size_t)yH * IMG + x0 + hx]
                  : 0.f;
          }
      }

      // ---- V loads (consumed in epilogue, far later) ----
      float v[16], vx[3] = {0.f, 0.f, 0.f};
      {
        const float* vb = Vf + (size_t)yw * IMG + x0 + xloc
                          + (size_t)kb * 4 * plane;
        if (ih) {
          const float* vb1 = vb + (size_t)19 * plane;
          #pragma unroll
          for (int r = 0; r < 16; ++r)
            v[r] = vb1[(size_t)((r & 3) + 8 * (r >> 2)) * plane];
        } else {
          #pragma unroll
          for (int r = 0; r < 8; ++r)
            v[r] = vb[(size_t)((r & 3) + 8 * (r >> 2)) * plane];
          if (kb == 0) {
            vx[0] = vb[(size_t)16 * plane];
            vx[1] = vb[(size_t)17 * plane];
            vx[2] = vb[(size_t)18 * plane];
          }
        }
      }

      // ---- A base (static slot, no ring) ----
      const int lr = (ih ? 19 : 0) + 2 * s + ypar + n;   // local row
      const char* pA = (const char*)fr32 + (4 * g + kb) * GR_B + lr * 16;
      const uint32_t* hrow = hL + (ypar * 64 + xloc) * HP;
      // g=1,kb=1,q=5 would read granule 15 (not staged); B there is all-zero
      // (taps j>=57) -> redirect to a staged granule: finite * 0 = 0.
      const bool q5fix = (g & kb) != 0;

      // ---- MFMA cluster: q-outer (runtime -> bq not hoistable), c-inner ----
      f32x16 D0, D1, D2;
      #pragma unroll
      for (int e = 0; e < 16; ++e) { D0[e] = 0.f; D1[e] = 0.f; D2[e] = 0.f; }

      __builtin_amdgcn_s_setprio(1);
      #pragma unroll 1
      for (int q = 0; q < NQ; ++q) {
        uint4 bq;
        {
          int j0 = 16 * q + 8 * kb - n;
          int pb = j0 >> 1;
          uint32_t rd[5];
          #pragma unroll
          for (int ww = 0; ww < 5; ++ww) {
            int pw = pb + ww;
            bool ok = (unsigned)pw <= 25u;
            uint32_t vr = hrow[ok ? pw : 0];
            rd[ww] = ok ? vr : 0u;
          }
          uint32_t fv[4];
          #pragma unroll
          for (int v2 = 0; v2 < 4; ++v2) {
            uint32_t al =
                (uint32_t)((((uint64_t)rd[v2 + 1] << 32) | rd[v2]) >> 16);
            fv[v2] = (n & 1) ? al : rd[v2];
          }
          bq = make_uint4(fv[0], fv[1], fv[2], fv[3]);
        }
        int aoff = q * (2 * GR_B);
        if (q == 5 && q5fix) aoff -= 2 * GR_B;
        const char* pAq = pA + aoff;
        const f16x8 A0 = *(const f16x8*)(pAq);
        D0 = __builtin_amdgcn_mfma_f32_32x32x16_f16(
                 A0, __builtin_bit_cast(f16x8, bq), D0, 0, 0, 0);
        const f16x8 A1 = *(const f16x8*)(pAq + CH_B);
        D1 = __builtin_amdgcn_mfma_f32_32x32x16_f16(
                 A1, __builtin_bit_cast(f16x8, bq), D1, 0, 0, 0);
        const f16x8 A2 = *(const f16x8*)(pAq + 2 * CH_B);
        D2 = __builtin_amdgcn_mfma_f32_32x32x16_f16(
                 A2, __builtin_bit_cast(f16x8, bq), D2, 0, 0, 0);
      }
      __builtin_amdgcn_s_setprio(0);

      // ---- epilogue: V-weighted reduce of D, cross-kb fold ----
      float a0 = 0.f, a1 = 0.f, a2 = 0.f;
      if (ih) {
        #pragma unroll
        for (int r = 0; r < 16; ++r) {
          a0 += v[r] * D0[r]; a1 += v[r] * D1[r]; a2 += v[r] * D2[r];
        }
      } else {
        #pragma unroll
        for (int r = 0; r < 8; ++r) {
          a0 += v[r] * D0[r]; a1 += v[r] * D1[r]; a2 += v[r] * D2[r];
        }
        a0 += vx[0] * D0[8] + vx[1] * D0[9] + vx[2] * D0[10];
        a1 += vx[0] * D1[8] + vx[1] * D1[9] + vx[2] * D1[10];
        a2 += vx[0] * D2[8] + vx[1] * D2[9] + vx[2] * D2[10];
      }
      a0 += __shfl_xor(a0, 32, 64);
      a1 += __shfl_xor(a1, 32, 64);
      a2 += __shfl_xor(a2, 32, 64);

      if (l < 32) {
        exL[exidx(s, ih, g, ypar, 0, l)] = a0;
        exL[exidx(s, ih, g, ypar, 1, l)] = a1;
        exL[exidx(s, ih, g, ypar, 2, l)] = a2;
      }
    }

    // ---- final phase: reduce ih-halves, coalesced (RMW) store ----
    __syncthreads();
    #pragma unroll
    for (int t = 0; t < 3; ++t) {
      int oi = tid + NT * t;          // 1536 outputs
      int px = oi & 63, rem = oi >> 6;
      int c = rem % 3, r = rem / 3;
      int ss = r >> 1, yp = r & 1, gg = px >> 5, nn = px & 31;
      float val = exL[exidx(ss, 0, gg, yp, c, nn)]
                + exL[exidx(ss, 1, gg, yp, c, nn)];
      size_t oidx = ((size_t)(b * 3 + c) * IMG + y0 + r) * IMG + x0 + px;
      out[oidx] = (f == 0) ? val : (out[oidx] + val);
    }
  }
}

} // namespace

extern "C" void kernel_launch(void* const* d_in, const int* in_sizes, int n_in,
                              void* d_out, int out_size, void* d_ws, size_t ws_size,
                              hipStream_t stream)
{
  const float* frame0 = (const float*)d_in[0];
  const float* frame2 = (const float*)d_in[1];
  const float* V1 = (const float*)d_in[2];
  const float* H1 = (const float*)d_in[3];
  const float* V2 = (const float*)d_in[4];
  const float* H2 = (const float*)d_in[5];
  float* o = (float*)d_out;

  dim3 grid(IMG / XB, IMG / YB, 2);
  dim3 block(NT);
  hipLaunchKernelGGL(sepconv, grid, block, 0, stream,
                     frame0, frame2, V1, H1, V2, H2, o);
}

// Round 13
// 144.953 us; speedup vs baseline: 1.7836x; 1.1120x over previous
//
#include <hip/hip_runtime.h>
#include <stdint.h>

namespace {

typedef _Float16 f16x8 __attribute__((ext_vector_type(8)));
typedef float f32x16 __attribute__((ext_vector_type(16)));

__device__ __forceinline__ uint32_t pkrtz(float a, float b) {
  return __builtin_bit_cast(uint32_t, __builtin_amdgcn_cvt_pkrtz(a, b));
}

constexpr int IMG = 512, K = 51;
constexpr int NT = 512;     // 8 waves: (group g) x (row parity) x (i-half)
constexpr int XB = 64;      // pixels per block
constexpr int YB = 8;       // output rows per block
constexpr int NSS = YB / 2; // 4 supersteps
constexpr int FROWS = 59;   // static rows y0-25 .. y0+33 (no ring)
constexpr int FG = 15;      // 16B granules per channel-row = 120 f16 cols
constexpr int HP = 26;      // u32 pitch of H pair-table per x
constexpr int NQ = 6;       // K=16 chunks

constexpr int GR_B  = FROWS * 16;        // 944 B per granule
constexpr int CH_B  = FG * GR_B;         // 14160 B per channel
constexpr int FR_U32 = 3 * FG * FROWS;   // frame tile granule-quads (*4 u32)
constexpr int H_U32  = 2 * 64 * HP;      // 13312 B
constexpr int EX_F32 = 4 * 2 * 2 * 2 * 3 * 32;  // 12288 B
// LDS total: 42480 + 13312 + 12288 = 68080 B -> 2 blocks/CU, 16 waves/CU

__device__ __forceinline__ int exidx(int s, int ih, int g, int yp, int c, int n) {
  return ((((s * 2 + ih) * 2 + g) * 2 + yp) * 3 + c) * 32 + n;
}

__global__ __launch_bounds__(NT, 4)
void sepconv(const float* __restrict__ fr0, const float* __restrict__ fr2,
             const float* __restrict__ V1, const float* __restrict__ H1,
             const float* __restrict__ V2, const float* __restrict__ H2,
             float* __restrict__ out)
{
  __shared__ __align__(16) uint32_t fr32[FR_U32 * 4];
  __shared__ uint32_t hL[H_U32];
  __shared__ float exL[EX_F32];

  const int tid = threadIdx.x;
  const int l    = tid & 63;
  const int w    = tid >> 6;
  const int g    = w & 1;          // 32-px group
  const int ypar = (w >> 1) & 1;   // row parity
  const int ih   = w >> 2;         // i-half: 0 -> taps 0..18, 1 -> taps 19..50
  const int n    = l & 31;         // pixel in group
  const int kb   = l >> 5;         // k-half
  const int x0   = blockIdx.x * XB;
  const int y0   = blockIdx.y * YB;
  const int b    = blockIdx.z;
  const size_t plane = (size_t)IMG * IMG;
  const int xloc = 32 * g + n;

  // H staging role: 2 rows x 4 segments x 64 px = 512 threads exactly
  const int hx = tid & 63, hseg = (tid >> 6) & 3, hyy = tid >> 8;
  const int segp0 = (hseg == 0) ? 0 : (hseg == 1) ? 7 : (hseg == 2) ? 13 : 20;
  const int segn  = (hseg & 1) ? 6 : 7;

  #pragma unroll 1
  for (int f = 0; f < 2; ++f) {
    const float* __restrict__ Vf = (f ? V2 : V1) + (size_t)b * K * plane;
    const float* __restrict__ Hf = (f ? H2 : H1) + (size_t)b * K * plane;
    const float* __restrict__ frb = (f ? fr2 : fr0) + (size_t)b * 3 * plane;

    float ha[7], hb[7];     // distance-1 H carries

    __syncthreads();   // previous pass's LDS reads (incl. final phase) done

    // ---- prologue: H rows y0,y0+1 (loads issued first) ----
    float pha[7], phb[7];
    {
      const int yH = y0 + hyy;
      #pragma unroll
      for (int m = 0; m < 7; ++m)
        if (m < segn) {
          int p = segp0 + m, j0 = 2 * p;
          pha[m] = Hf[(size_t)j0 * plane + (size_t)yH * IMG + x0 + hx];
          phb[m] = (j0 + 1 <= 50)
                 ? Hf[(size_t)(j0 + 1) * plane + (size_t)yH * IMG + x0 + hx]
                 : 0.f;
        }
    }
    // ---- prologue: frame rows y0-25..y0+33 (10620 pair-tasks, 3 passes) ----
    #pragma unroll 1
    for (int pass = 0; pass < 3; ++pass) {
      float ta[7], tb[7];
      #pragma unroll
      for (int k2 = 0; k2 < 7; ++k2) {
        int task = tid + NT * (pass * 7 + k2);
        if (task < 10620) {
          int rr = task / 180; int rem = task - rr * 180;
          int c = rem / 60, pc = rem - c * 60;
          int row = min(max(y0 - 25 + rr, 0), IMG - 1);
          int ca = min(max(x0 - 25 + 2 * pc, 0), IMG - 1);
          int cb = min(max(x0 - 25 + 2 * pc + 1, 0), IMG - 1);
          const float* rp = frb + (size_t)c * plane + (size_t)row * IMG;
          ta[k2] = rp[ca]; tb[k2] = rp[cb];
        }
      }
      if (pass == 0) {   // H-table writes overlapped under pass-0 loads
        #pragma unroll
        for (int m = 0; m < 7; ++m)
          if (m < segn)
            hL[(hyy * 64 + hx) * HP + segp0 + m] = pkrtz(pha[m], phb[m]);
      }
      #pragma unroll
      for (int k2 = 0; k2 < 7; ++k2) {
        int task = tid + NT * (pass * 7 + k2);
        if (task < 10620) {
          int rr = task / 180; int rem = task - rr * 180;
          int c = rem / 60, pc = rem - c * 60;
          fr32[((c * FG + (pc >> 2)) * FROWS + rr) * 4 + (pc & 3)] =
              pkrtz(ta[k2], tb[k2]);
        }
      }
    }
    __syncthreads();

    #pragma unroll 1
    for (int s = 0; s < NSS; ++s) {
      const int y = y0 + 2 * s;
      if (s > 0) {
        __syncthreads();   // previous superstep's hL reads complete
        #pragma unroll
        for (int m = 0; m < 7; ++m)
          if (m < segn)
            hL[(hyy * 64 + hx) * HP + segp0 + m] = pkrtz(ha[m], hb[m]);
        __syncthreads();   // H table visible
      }
      const int yw = y + ypar;

      // ---- A base (static slot, no ring) ----
      const int lr = (ih ? 19 : 0) + 2 * s + ypar + n;   // local row
      const char* pA = (const char*)fr32 + (4 * g + kb) * GR_B + lr * 16;
      const uint32_t* hrow = hL + (ypar * 64 + xloc) * HP;
      // g=1,kb=1,q=5 would read granule 15 (not staged); B there is all-zero
      // (taps j>=57) -> redirect to a staged granule: finite * 0 = 0.
      const bool q5fix = (g & kb) != 0;

      // ---- MFMA cluster: q-outer (runtime -> bq not hoistable), c-inner.
      //      Minimal live set: bq + temps + bases + D (AGPR). V and H-carry
      //      loads deliberately issued AFTER this loop (lifetime surgery).
      f32x16 D0, D1, D2;
      #pragma unroll
      for (int e = 0; e < 16; ++e) { D0[e] = 0.f; D1[e] = 0.f; D2[e] = 0.f; }

      __builtin_amdgcn_s_setprio(1);
      #pragma unroll 1
      for (int q = 0; q < NQ; ++q) {
        uint4 bq;
        {
          int j0 = 16 * q + 8 * kb - n;
          int pb = j0 >> 1;
          uint32_t rd[5];
          #pragma unroll
          for (int ww = 0; ww < 5; ++ww) {
            int pw = pb + ww;
            bool ok = (unsigned)pw <= 25u;
            uint32_t vr = hrow[ok ? pw : 0];
            rd[ww] = ok ? vr : 0u;
          }
          uint32_t fv[4];
          #pragma unroll
          for (int v2 = 0; v2 < 4; ++v2) {
            uint32_t al =
                (uint32_t)((((uint64_t)rd[v2 + 1] << 32) | rd[v2]) >> 16);
            fv[v2] = (n & 1) ? al : rd[v2];
          }
          bq = make_uint4(fv[0], fv[1], fv[2], fv[3]);
        }
        int aoff = q * (2 * GR_B);
        if (q == 5 && q5fix) aoff -= 2 * GR_B;
        const char* pAq = pA + aoff;
        const f16x8 A0 = *(const f16x8*)(pAq);
        D0 = __builtin_amdgcn_mfma_f32_32x32x16_f16(
                 A0, __builtin_bit_cast(f16x8, bq), D0, 0, 0, 0);
        const f16x8 A1 = *(const f16x8*)(pAq + CH_B);
        D1 = __builtin_amdgcn_mfma_f32_32x32x16_f16(
                 A1, __builtin_bit_cast(f16x8, bq), D1, 0, 0, 0);
        const f16x8 A2 = *(const f16x8*)(pAq + 2 * CH_B);
        D2 = __builtin_amdgcn_mfma_f32_32x32x16_f16(
                 A2, __builtin_bit_cast(f16x8, bq), D2, 0, 0, 0);
      }
      __builtin_amdgcn_s_setprio(0);

      // ---- V loads issued now (short live range; TLP covers latency) ----
      float v[16], vx[3] = {0.f, 0.f, 0.f};
      {
        const float* vb = Vf + (size_t)yw * IMG + x0 + xloc
                          + (size_t)kb * 4 * plane;
        if (ih) {
          const float* vb1 = vb + (size_t)19 * plane;
          #pragma unroll
          for (int r = 0; r < 16; ++r)
            v[r] = vb1[(size_t)((r & 3) + 8 * (r >> 2)) * plane];
        } else {
          #pragma unroll
          for (int r = 0; r < 8; ++r)
            v[r] = vb[(size_t)((r & 3) + 8 * (r >> 2)) * plane];
          if (kb == 0) {
            vx[0] = vb[(size_t)16 * plane];
            vx[1] = vb[(size_t)17 * plane];
            vx[2] = vb[(size_t)18 * plane];
          }
        }
      }
      // ---- H-carry loads for s+1 (consumed after next barrier) ----
      if (s + 1 < NSS) {
        const int yH = y + 2 + hyy;
        #pragma unroll
        for (int m = 0; m < 7; ++m)
          if (m < segn) {
            int p = segp0 + m, j0 = 2 * p;
            ha[m] = Hf[(size_t)j0 * plane + (size_t)yH * IMG + x0 + hx];
            hb[m] = (j0 + 1 <= 50)
                  ? Hf[(size_t)(j0 + 1) * plane + (size_t)yH * IMG + x0 + hx]
                  : 0.f;
          }
      }

      // ---- epilogue: V-weighted reduce of D, cross-kb fold ----
      float a0 = 0.f, a1 = 0.f, a2 = 0.f;
      if (ih) {
        #pragma unroll
        for (int r = 0; r < 16; ++r) {
          a0 += v[r] * D0[r]; a1 += v[r] * D1[r]; a2 += v[r] * D2[r];
        }
      } else {
        #pragma unroll
        for (int r = 0; r < 8; ++r) {
          a0 += v[r] * D0[r]; a1 += v[r] * D1[r]; a2 += v[r] * D2[r];
        }
        a0 += vx[0] * D0[8] + vx[1] * D0[9] + vx[2] * D0[10];
        a1 += vx[0] * D1[8] + vx[1] * D1[9] + vx[2] * D1[10];
        a2 += vx[0] * D2[8] + vx[1] * D2[9] + vx[2] * D2[10];
      }
      a0 += __shfl_xor(a0, 32, 64);
      a1 += __shfl_xor(a1, 32, 64);
      a2 += __shfl_xor(a2, 32, 64);

      // ---- partials: f=0 writes, f=1 accumulates (same thread, same slot) --
      if (l < 32) {
        if (f == 0) {
          exL[exidx(s, ih, g, ypar, 0, l)] = a0;
          exL[exidx(s, ih, g, ypar, 1, l)] = a1;
          exL[exidx(s, ih, g, ypar, 2, l)] = a2;
        } else {
          exL[exidx(s, ih, g, ypar, 0, l)] += a0;
          exL[exidx(s, ih, g, ypar, 1, l)] += a1;
          exL[exidx(s, ih, g, ypar, 2, l)] += a2;
        }
      }
    }
  }

  // ---- final phase: reduce ih-halves, coalesced store (no out read) ----
  __syncthreads();
  #pragma unroll
  for (int t = 0; t < 3; ++t) {
    int oi = tid + NT * t;          // 1536 outputs
    int px = oi & 63, rem = oi >> 6;
    int c = rem % 3, r = rem / 3;
    int ss = r >> 1, yp = r & 1, gg = px >> 5, nn = px & 31;
    float val = exL[exidx(ss, 0, gg, yp, c, nn)]
              + exL[exidx(ss, 1, gg, yp, c, nn)];
    size_t oidx = ((size_t)(b * 3 + c) * IMG + y0 + r) * IMG + x0 + px;
    out[oidx] = val;
  }
}

} // namespace

extern "C" void kernel_launch(void* const* d_in, const int* in_sizes, int n_in,
                              void* d_out, int out_size, void* d_ws, size_t ws_size,
                              hipStream_t stream)
{
  const float* frame0 = (const float*)d_in[0];
  const float* frame2 = (const float*)d_in[1];
  const float* V1 = (const float*)d_in[2];
  const float* H1 = (const float*)d_in[3];
  const float* V2 = (const float*)d_in[4];
  const float* H2 = (const float*)d_in[5];
  float* o = (float*)d_out;

  dim3 grid(IMG / XB, IMG / YB, 2);
  dim3 block(NT);
  hipLaunchKernelGGL(sepconv, grid, block, 0, stream,
                     frame0, frame2, V1, H1, V2, H2, o);
}